// Round 3
// baseline (120.764 us; speedup 1.0000x reference)
//
#include <hip/hip_runtime.h>
#include <cmath>

#define DIM 128
#define NHALF 4096
#define NROWS 8192
// FRAG_SCALE^2 = log2(e)/tau = 1.4426950408889634/0.5
#define FRAG_SCALE 1.69864368f

typedef __attribute__((ext_vector_type(8))) short bf16x8;
typedef __attribute__((ext_vector_type(4))) float f32x4;

static __device__ __forceinline__ unsigned short f32_to_bf16(float f) {
  unsigned int u = __float_as_uint(f);
  u = (u + 0x7FFFu + ((u >> 16) & 1u)) >> 16;
  return (unsigned short)u;
}

// async global->LDS, 16 B per lane; lds base must be wave-uniform.
static __device__ __forceinline__ void gload_lds16(const void* g, void* l) {
  __builtin_amdgcn_global_load_lds(
      (const __attribute__((address_space(1))) unsigned int*)g,
      (__attribute__((address_space(3))) unsigned int*)l, 16, 0, 0);
}

// tile index k within pair p -> (bi,bj). Band p has 64-p tiles (bj=p..63),
// band 63-p has p+1 tiles (bj=63-p..63); 65 total per pair.
static __device__ __forceinline__ void tile_of(int p, int k, int* bi,
                                               int* bj) {
  int c0 = 64 - p;
  if (k < c0) {
    *bi = p;
    *bj = p + k;
  } else {
    *bi = 63 - p;
    *bj = 63 - p + (k - c0);
  }
}

// One wave per pair r in [0,4096): L2-normalize z_i[r], z_j[r], scale by
// sqrt(log2e/tau), store bf16 rows r and r+4096; pos[r]=pos[r+4096] =
// dot(zi,zj)/(|zi||zj|)/tau computed in fp32. Also zeroes out[0].
__global__ __launch_bounds__(256) void prep_kernel(
    const float* __restrict__ z_i, const float* __restrict__ z_j,
    unsigned short* __restrict__ A, float* __restrict__ pos,
    float* __restrict__ out) {
  int wave = threadIdx.x >> 6;
  int lane = threadIdx.x & 63;
  int r = blockIdx.x * 4 + wave;
  if (blockIdx.x == 0 && threadIdx.x == 0) out[0] = 0.0f;
  float2 a = *(const float2*)(z_i + (size_t)r * DIM + 2 * lane);
  float2 b = *(const float2*)(z_j + (size_t)r * DIM + 2 * lane);
  float sa = a.x * a.x + a.y * a.y;
  float sb = b.x * b.x + b.y * b.y;
  float dp = a.x * b.x + a.y * b.y;
#pragma unroll
  for (int off = 1; off < 64; off <<= 1) {
    sa += __shfl_xor(sa, off);
    sb += __shfl_xor(sb, off);
    dp += __shfl_xor(dp, off);
  }
  float na = fmaxf(sqrtf(sa), 1e-8f);
  float nb = fmaxf(sqrtf(sb), 1e-8f);
  float si = FRAG_SCALE / na;
  float sj = FRAG_SCALE / nb;
  unsigned int pa = (unsigned int)f32_to_bf16(a.x * si) |
                    ((unsigned int)f32_to_bf16(a.y * si) << 16);
  unsigned int pb = (unsigned int)f32_to_bf16(b.x * sj) |
                    ((unsigned int)f32_to_bf16(b.y * sj) << 16);
  ((unsigned int*)A)[(size_t)r * (DIM / 2) + lane] = pa;
  ((unsigned int*)A)[(size_t)(r + NHALF) * (DIM / 2) + lane] = pb;
  if (lane == 0) {
    float p = dp / (na * nb) * 2.0f;  // /tau, tau=0.5
    pos[r] = p;
    pos[r + NHALF] = p;
  }
}

// Persistent upper-triangle tiling: 256 blocks, block b owns pair p=b>>3
// (bands p and 63-p, exactly 65 tiles), slice s=b&7 of it (8-9 tiles).
// A-panel staged once per band; B-panel double-buffered: stage of tile k+1
// overlaps MFMA+epilogue of tile k (single vmcnt-drain barrier per tile).
// Staging uses global-source XOR swizzle + linear LDS dest + swizzled
// ds_read (bank-conflict-free). Epilogue: LDS reduction of row/col
// exp-sums, disjoint-slot stores into partials[64][8192] — no global
// atomics.
__global__ __launch_bounds__(256) void simexp_kernel(
    const unsigned short* __restrict__ A, float* __restrict__ partials) {
  const int tid = threadIdx.x;
  const int lane = tid & 63;
  const int w = tid >> 6;
  const int q = lane >> 4;
  const int n = lane & 15;

  __shared__ alignas(16) unsigned short As[128 * DIM];      // 32 KB
  __shared__ alignas(16) unsigned short Bs[2][128 * DIM];   // 64 KB
  __shared__ float redR[128];
  __shared__ float redC[128];

  const int p = blockIdx.x >> 3;
  const int s = blockIdx.x & 7;
  const int kb = (65 * s) >> 3;
  const int ke = (65 * (s + 1)) >> 3;

  const int c = lane & 15;
  const int rsub = lane >> 4;
  // stage one 128-row panel (32 KB): 8 chunks/wave, source XOR-swizzled.
#define STAGE(gbase, lbase)                                          \
  {                                                                  \
    const unsigned short* g_ = (gbase);                              \
    char* l_ = (char*)(lbase);                                       \
    _Pragma("unroll") for (int i_ = 0; i_ < 8; i_++) {               \
      int chunk_ = i_ * 4 + w;                                       \
      int row_ = chunk_ * 4 + rsub;                                  \
      int srcoff_ = row_ * DIM + ((c ^ (row_ & 7)) << 3);            \
      gload_lds16(g_ + srcoff_, l_ + chunk_ * 1024);                 \
    }                                                                \
  }

  // prologue: stage A(band of first tile) + B(first tile), zero red
  int bi, bj;
  tile_of(p, kb, &bi, &bj);
  int curband = bi;
  STAGE(A + (size_t)bi * 128 * DIM, As);
  STAGE(A + (size_t)bj * 128 * DIM, Bs[0]);
  if (tid < 128) redR[tid] = 0.0f;
  else redC[tid - 128] = 0.0f;
  __syncthreads();  // drains vmcnt(0): panels + red ready

  int cur = 0;
  for (int k = kb; k < ke; ++k) {
    tile_of(p, k, &bi, &bj);
    if (bi != curband) {  // band switch (<=1 per block): restage A
      STAGE(A + (size_t)bi * 128 * DIM, As);
      __syncthreads();
      curband = bi;
    }
    // prefetch next tile's B-panel into the other buffer (overlaps compute)
    if (k + 1 < ke) {
      int nbi, nbj;
      tile_of(p, k + 1, &nbi, &nbj);
      STAGE(A + (size_t)nbj * 128 * DIM, Bs[cur ^ 1]);
    }

    const int rbBase = bi * 128;
    const int cbBase = bj * 128;
    const int wrow = (w & 1) * 64;
    const int wcol = (w >> 1) * 64;
    const unsigned short* Bcur = Bs[cur];

    f32x4 acc[16];
#pragma unroll
    for (int i = 0; i < 16; i++)
#pragma unroll
      for (int j = 0; j < 4; j++) acc[i][j] = 0.0f;

#pragma unroll
    for (int kc = 0; kc < 4; kc++) {
      bf16x8 af[4], bfr[4];
      const int cg = kc * 4 + q;  // 16B column-group index 0..15
#pragma unroll
      for (int mi = 0; mi < 4; mi++) {
        int row = wrow + mi * 16 + n;
        af[mi] = *(const bf16x8*)(As + row * DIM + ((cg ^ (row & 7)) << 3));
      }
#pragma unroll
      for (int ni = 0; ni < 4; ni++) {
        int row = wcol + ni * 16 + n;
        bfr[ni] = *(const bf16x8*)(Bcur + row * DIM + ((cg ^ (row & 7)) << 3));
      }
#pragma unroll
      for (int mi = 0; mi < 4; mi++)
#pragma unroll
        for (int ni = 0; ni < 4; ni++)
          acc[mi * 4 + ni] = __builtin_amdgcn_mfma_f32_16x16x32_bf16(
              af[mi], bfr[ni], acc[mi * 4 + ni], 0, 0, 0);
    }

    // epilogue: exp2, diagonal mask, row + column accumulation (registers)
    float eaccR[16];
    float eaccC[4];
#pragma unroll
    for (int i = 0; i < 16; i++) eaccR[i] = 0.0f;
#pragma unroll
    for (int i = 0; i < 4; i++) eaccC[i] = 0.0f;
#pragma unroll
    for (int mi = 0; mi < 4; mi++) {
#pragma unroll
      for (int ni = 0; ni < 4; ni++) {
#pragma unroll
        for (int rg = 0; rg < 4; rg++) {
          float v = acc[mi * 4 + ni][rg];
          float e = __builtin_amdgcn_exp2f(v);
          int grow = rbBase + wrow + mi * 16 + q * 4 + rg;
          int gcol = cbBase + wcol + ni * 16 + n;
          e = (grow == gcol) ? 0.0f : e;
          eaccR[mi * 4 + rg] += e;
          eaccC[ni] += e;
        }
      }
    }

    // row sums: reduce across n (16 lanes per q-group) -> LDS (cross-wave)
#pragma unroll
    for (int mi = 0; mi < 4; mi++) {
#pragma unroll
      for (int rg = 0; rg < 4; rg++) {
        float v = eaccR[mi * 4 + rg];
        v += __shfl_xor(v, 1);
        v += __shfl_xor(v, 2);
        v += __shfl_xor(v, 4);
        v += __shfl_xor(v, 8);
        if (n == 0) atomicAdd(&redR[wrow + mi * 16 + q * 4 + rg], v);
      }
    }
    // column sums (symmetry credit): reduce across q -> LDS (cross-wave)
#pragma unroll
    for (int ni = 0; ni < 4; ni++) {
      float v = eaccC[ni];
      v += __shfl_xor(v, 16);
      v += __shfl_xor(v, 32);
      if (lane < 16) atomicAdd(&redC[wcol + ni * 16 + n], v);
    }
    __syncthreads();  // red complete; B-prefetch drained (vmcnt 0)

    // disjoint-slot partial stores + rezero red for next tile.
    // Slot map: row-side -> slot (bj-bi), col-side -> slot (64-(bj-bi));
    // per row-block slots 0..63 each filled exactly once over all tiles.
    if (tid < 128) {
      partials[(size_t)(bj - bi) * NROWS + rbBase + tid] = redR[tid];
      redR[tid] = 0.0f;
    } else {
      if (bi != bj)
        partials[(size_t)(64 - (bj - bi)) * NROWS + cbBase + (tid - 128)] =
            redC[tid - 128];
      redC[tid - 128] = 0.0f;
    }
    __syncthreads();  // stores/rezero visible; next buffer ready
    cur ^= 1;
  }
#undef STAGE
}

// loss = mean over rows of log(rowsum) - pos; rowsum = sum of the row's 64
// partial slots. 32 blocks x 256 threads, one row per thread; per-k loads
// are coalesced across the block. One atomicAdd on out[0] per block.
__global__ __launch_bounds__(256) void finalize_kernel(
    const float* __restrict__ partials, const float* __restrict__ pos,
    float* __restrict__ out) {
  int tid = threadIdx.x;
  int r = blockIdx.x * 256 + tid;
  float s = 0.0f;
#pragma unroll
  for (int k = 0; k < 64; k++) s += partials[(size_t)k * NROWS + r];
  float local = logf(s) - pos[r];
#pragma unroll
  for (int off = 1; off < 64; off <<= 1) local += __shfl_xor(local, off);
  __shared__ float wsum[4];
  if ((tid & 63) == 0) wsum[tid >> 6] = local;
  __syncthreads();
  if (tid == 0)
    atomicAdd(out, (wsum[0] + wsum[1] + wsum[2] + wsum[3]) *
                       (1.0f / (float)NROWS));
}

extern "C" void kernel_launch(void* const* d_in, const int* in_sizes, int n_in,
                              void* d_out, int out_size, void* d_ws,
                              size_t ws_size, hipStream_t stream) {
  const float* z_i = (const float*)d_in[0];
  const float* z_j = (const float*)d_in[1];
  float* out = (float*)d_out;

  unsigned short* A = (unsigned short*)d_ws;               // 8192*128 bf16 = 2 MB
  float* partials = (float*)((char*)d_ws + (1u << 21));    // 64*8192 f32 = 2 MB
  float* pos = (float*)((char*)d_ws + (2u << 21));         // 32 KB

  prep_kernel<<<NHALF / 4, 256, 0, stream>>>(z_i, z_j, A, pos, out);
  simexp_kernel<<<256, 256, 0, stream>>>(A, partials);
  finalize_kernel<<<32, 256, 0, stream>>>(partials, pos, out);
}

// Round 4
// 107.514 us; speedup vs baseline: 1.1232x; 1.1232x over previous
//
#include <hip/hip_runtime.h>
#include <cmath>

#define DIM 128
#define NHALF 4096
#define NROWS 8192
#define NB 128       // number of 64-row bands
#define NTILES 8256  // NB*(NB+1)/2 upper-triangle 64x64 tiles
// FRAG_SCALE^2 = log2(e)/tau = 1.4426950408889634/0.5
#define FRAG_SCALE 1.69864368f

typedef __attribute__((ext_vector_type(8))) short bf16x8;
typedef __attribute__((ext_vector_type(4))) float f32x4;

static __device__ __forceinline__ unsigned short f32_to_bf16(float f) {
  unsigned int u = __float_as_uint(f);
  u = (u + 0x7FFFu + ((u >> 16) & 1u)) >> 16;
  return (unsigned short)u;
}

// One wave per pair r in [0,4096): L2-normalize z_i[r], z_j[r], scale by
// sqrt(log2e/tau), store bf16 rows r and r+4096; pos[r]=pos[r+4096] =
// dot(zi,zj)/(|zi||zj|)/tau computed in fp32. Also zeroes out[0].
__global__ __launch_bounds__(256) void prep_kernel(
    const float* __restrict__ z_i, const float* __restrict__ z_j,
    unsigned short* __restrict__ A, float* __restrict__ pos,
    float* __restrict__ out) {
  int wave = threadIdx.x >> 6;
  int lane = threadIdx.x & 63;
  int r = blockIdx.x * 4 + wave;
  if (blockIdx.x == 0 && threadIdx.x == 0) out[0] = 0.0f;
  float2 a = *(const float2*)(z_i + (size_t)r * DIM + 2 * lane);
  float2 b = *(const float2*)(z_j + (size_t)r * DIM + 2 * lane);
  float sa = a.x * a.x + a.y * a.y;
  float sb = b.x * b.x + b.y * b.y;
  float dp = a.x * b.x + a.y * b.y;
#pragma unroll
  for (int off = 1; off < 64; off <<= 1) {
    sa += __shfl_xor(sa, off);
    sb += __shfl_xor(sb, off);
    dp += __shfl_xor(dp, off);
  }
  float na = fmaxf(sqrtf(sa), 1e-8f);
  float nb = fmaxf(sqrtf(sb), 1e-8f);
  float si = FRAG_SCALE / na;
  float sj = FRAG_SCALE / nb;
  unsigned int pa = (unsigned int)f32_to_bf16(a.x * si) |
                    ((unsigned int)f32_to_bf16(a.y * si) << 16);
  unsigned int pb = (unsigned int)f32_to_bf16(b.x * sj) |
                    ((unsigned int)f32_to_bf16(b.y * sj) << 16);
  ((unsigned int*)A)[(size_t)r * (DIM / 2) + lane] = pa;
  ((unsigned int*)A)[(size_t)(r + NHALF) * (DIM / 2) + lane] = pb;
  if (lane == 0) {
    float p = dp / (na * nb) * 2.0f;  // /tau, tau=0.5
    pos[r] = p;
    pos[r + NHALF] = p;
  }
}

// One wave = one independent 64x64 upper-triangle tile (ti<=tj over 128
// bands of 64 rows). No LDS, no barriers, no atomics: 16 waves/CU
// (launch_bounds forces <=128 VGPR) free-run and hide L2 latency via TLP.
// MFMA operands load directly from L2-resident A. Row exp-sums reduce
// in-wave (4 shuffles) and store to disjoint slot (tj-ti) of
// partials[128][8192]; col-side symmetry credit reduces with 2 shuffles and
// stores to slot 128-(tj-ti). Per band, slots 0..127 are each written
// exactly once across all tiles -> no zero-init, no collisions.
__global__ __launch_bounds__(256, 4) void simexp_kernel(
    const unsigned short* __restrict__ A, float* __restrict__ partials) {
  const int lane = threadIdx.x & 63;
  const int w = threadIdx.x >> 6;
  const int q = lane >> 4;
  const int n = lane & 15;

  // decode wave-tile index g -> (ti, tj), ti <= tj < 128
  int g = blockIdx.x * 4 + w;
  int ti = (int)((257.0f - sqrtf(66049.0f - 8.0f * (float)g)) * 0.5f);
  int start = 128 * ti - (ti * (ti - 1)) / 2;
  if (g < start) {
    ti--;
    start = 128 * ti - (ti * (ti - 1)) / 2;
  } else if (g >= start + (128 - ti)) {
    start += 128 - ti;
    ti++;
  }
  int tj = ti + (g - start);
  const bool diag = (ti == tj);

  const unsigned short* Arow = A + (size_t)ti * 64 * DIM;
  const unsigned short* Brow = A + (size_t)tj * 64 * DIM;

  f32x4 acc[16];
#pragma unroll
  for (int i = 0; i < 16; i++)
#pragma unroll
    for (int j = 0; j < 4; j++) acc[i][j] = 0.0f;

#pragma unroll
  for (int kc = 0; kc < 4; kc++) {
    bf16x8 af[4], bfr[4];
#pragma unroll
    for (int mi = 0; mi < 4; mi++)
      af[mi] = *(const bf16x8*)(Arow + (mi * 16 + n) * DIM + kc * 32 + q * 8);
#pragma unroll
    for (int ni = 0; ni < 4; ni++)
      bfr[ni] = *(const bf16x8*)(Brow + (ni * 16 + n) * DIM + kc * 32 + q * 8);
#pragma unroll
    for (int mi = 0; mi < 4; mi++)
#pragma unroll
      for (int ni = 0; ni < 4; ni++)
        acc[mi * 4 + ni] = __builtin_amdgcn_mfma_f32_16x16x32_bf16(
            af[mi], bfr[ni], acc[mi * 4 + ni], 0, 0, 0);
  }

  // epilogue: exp2, (diag-only) mask, row + column accumulation in regs
  float eaccR[16];
  float eaccC[4];
#pragma unroll
  for (int i = 0; i < 16; i++) eaccR[i] = 0.0f;
#pragma unroll
  for (int i = 0; i < 4; i++) eaccC[i] = 0.0f;
  if (diag) {
#pragma unroll
    for (int mi = 0; mi < 4; mi++)
#pragma unroll
      for (int ni = 0; ni < 4; ni++)
#pragma unroll
        for (int rg = 0; rg < 4; rg++) {
          float e = __builtin_amdgcn_exp2f(acc[mi * 4 + ni][rg]);
          // local row/col within tile; ti==tj so global offsets cancel
          e = ((mi * 16 + q * 4 + rg) == (ni * 16 + n)) ? 0.0f : e;
          eaccR[mi * 4 + rg] += e;
          eaccC[ni] += e;
        }
  } else {
#pragma unroll
    for (int mi = 0; mi < 4; mi++)
#pragma unroll
      for (int ni = 0; ni < 4; ni++)
#pragma unroll
        for (int rg = 0; rg < 4; rg++) {
          float e = __builtin_amdgcn_exp2f(acc[mi * 4 + ni][rg]);
          eaccR[mi * 4 + rg] += e;
          eaccC[ni] += e;
        }
  }

  const int dslot = tj - ti;
  // row sums: reduce across n (xor 1,2,4,8 within each q-group), store
  float* prow = partials + (size_t)dslot * NROWS + ti * 64;
#pragma unroll
  for (int mi = 0; mi < 4; mi++) {
#pragma unroll
    for (int rg = 0; rg < 4; rg++) {
      float v = eaccR[mi * 4 + rg];
      v += __shfl_xor(v, 1);
      v += __shfl_xor(v, 2);
      v += __shfl_xor(v, 4);
      v += __shfl_xor(v, 8);
      if (n == 0) prow[mi * 16 + q * 4 + rg] = v;
    }
  }
  // column sums (symmetry credit): reduce across q (xor 16,32), store
  if (!diag) {
    float* pcol = partials + (size_t)(128 - dslot) * NROWS + tj * 64;
#pragma unroll
    for (int ni = 0; ni < 4; ni++) {
      float v = eaccC[ni];
      v += __shfl_xor(v, 16);
      v += __shfl_xor(v, 32);
      if (lane < 16) pcol[ni * 16 + lane] = v;
    }
  }
}

// loss = mean over rows of log(rowsum) - pos; rowsum = sum of the row's
// 128 partial slots. 256 blocks x 256 threads: block handles 32 rows with
// an 8-way k-split (tid = ks*32 + rr), LDS reduce, one atomic per block.
__global__ __launch_bounds__(256) void finalize_kernel(
    const float* __restrict__ partials, const float* __restrict__ pos,
    float* __restrict__ out) {
  int tid = threadIdx.x;
  int rr = tid & 31;
  int ks = tid >> 5;  // 0..7
  int r = blockIdx.x * 32 + rr;
  float s = 0.0f;
#pragma unroll
  for (int k = 0; k < 16; k++)
    s += partials[(size_t)(ks * 16 + k) * NROWS + r];
  __shared__ float red[8][32];
  red[ks][rr] = s;
  __syncthreads();
  if (tid < 32) {
    float t = 0.0f;
#pragma unroll
    for (int k2 = 0; k2 < 8; k2++) t += red[k2][tid];
    float local = logf(t) - pos[blockIdx.x * 32 + tid];
#pragma unroll
    for (int off = 1; off < 32; off <<= 1) local += __shfl_xor(local, off);
    if (tid == 0) atomicAdd(out, local * (1.0f / (float)NROWS));
  }
}

extern "C" void kernel_launch(void* const* d_in, const int* in_sizes, int n_in,
                              void* d_out, int out_size, void* d_ws,
                              size_t ws_size, hipStream_t stream) {
  const float* z_i = (const float*)d_in[0];
  const float* z_j = (const float*)d_in[1];
  float* out = (float*)d_out;

  unsigned short* A = (unsigned short*)d_ws;             // 8192*128 bf16 = 2 MB
  float* partials = (float*)((char*)d_ws + (1u << 21));  // 128*8192 f32 = 4 MB
  float* pos = (float*)((char*)d_ws + (3u << 21));       // 32 KB

  prep_kernel<<<NHALF / 4, 256, 0, stream>>>(z_i, z_j, A, pos, out);
  simexp_kernel<<<NTILES / 4, 256, 0, stream>>>(A, partials);
  finalize_kernel<<<NROWS / 32, 256, 0, stream>>>(partials, pos, out);
}

// Round 5
// 85.612 us; speedup vs baseline: 1.4106x; 1.2558x over previous
//
#include <hip/hip_runtime.h>
#include <cmath>

#define DIM 128
#define NHALF 4096
#define NROWS 8192
#define NB 128       // number of 64-row bands
#define NTILES 8256  // NB*(NB+1)/2 upper-triangle 64x64 tiles
// FRAG_SCALE^2 = log2(e)/tau = 1.4426950408889634/0.5
#define FRAG_SCALE 1.69864368f

typedef __attribute__((ext_vector_type(8))) short bf16x8;
typedef __attribute__((ext_vector_type(4))) float f32x4;

static __device__ __forceinline__ unsigned short f32_to_bf16(float f) {
  unsigned int u = __float_as_uint(f);
  u = (u + 0x7FFFu + ((u >> 16) & 1u)) >> 16;
  return (unsigned short)u;
}

// Fragment-major layout of the normalized bf16 matrix A_f:
//   group g = row>>4 (0..511), page = g*4 + kc (1 KB each).
//   Within a page: 16B chunk at offset (q*16 + n)*16 holds
//   row g*16+n, cols kc*32 + q*8 .. +8.
// This makes every MFMA fragment load `base + lane*16` -> 64 lanes x 16 B
// fully contiguous (ideal coalescing; no 16-way gather).

// One wave per pair r in [0,4096): L2-normalize z_i[r], z_j[r], scale by
// sqrt(log2e/tau), write bf16 rows r and r+4096 in fragment-major order;
// pos[r]=pos[r+4096] = dot/(|zi||zj|)/tau in fp32. Also zeroes out[0].
__global__ __launch_bounds__(256) void prep_kernel(
    const float* __restrict__ z_i, const float* __restrict__ z_j,
    unsigned int* __restrict__ A, float* __restrict__ pos,
    float* __restrict__ out) {
  int wave = threadIdx.x >> 6;
  int lane = threadIdx.x & 63;
  int r = blockIdx.x * 4 + wave;
  if (blockIdx.x == 0 && threadIdx.x == 0) out[0] = 0.0f;
  float2 a = *(const float2*)(z_i + (size_t)r * DIM + 2 * lane);
  float2 b = *(const float2*)(z_j + (size_t)r * DIM + 2 * lane);
  float sa = a.x * a.x + a.y * a.y;
  float sb = b.x * b.x + b.y * b.y;
  float dp = a.x * b.x + a.y * b.y;
#pragma unroll
  for (int off = 1; off < 64; off <<= 1) {
    sa += __shfl_xor(sa, off);
    sb += __shfl_xor(sb, off);
    dp += __shfl_xor(dp, off);
  }
  float na = fmaxf(sqrtf(sa), 1e-8f);
  float nb = fmaxf(sqrtf(sb), 1e-8f);
  float si = FRAG_SCALE / na;
  float sj = FRAG_SCALE / nb;
  unsigned int pa = (unsigned int)f32_to_bf16(a.x * si) |
                    ((unsigned int)f32_to_bf16(a.y * si) << 16);
  unsigned int pb = (unsigned int)f32_to_bf16(b.x * sj) |
                    ((unsigned int)f32_to_bf16(b.y * sj) << 16);
  // fragment-major scatter store (lane holds cols 2*lane, 2*lane+1):
  // kc = lane>>4, q = (lane>>2)&3, byte-quad b = lane&3, n = r&15.
  int rg = r >> 4;
  int n = r & 15;
  int kc = lane >> 4;
  int q = (lane >> 2) & 3;
  int bq = lane & 3;
  int off4 = rg * 1024 + kc * 256 + q * 64 + n * 4 + bq;
  A[off4] = pa;
  A[off4 + 262144] = pb;  // z_j groups start at group 256
  if (lane == 0) {
    float p = dp / (na * nb) * 2.0f;  // /tau, tau=0.5
    pos[r] = p;
    pos[r + NHALF] = p;
  }
}

// One wave = one independent 64x64 upper-triangle tile (ti<=tj over 128
// bands of 64 rows). No LDS, no barriers, no atomics. Fragment loads are
// fully coalesced (fragment-major A), double-buffered across kc so MFMAs
// overlap the next chunk's loads. Row exp-sums reduce in-wave and store to
// disjoint slot (tj-ti) of partials[128][8192]; col-side symmetry credit
// stores to slot 128-(tj-ti). Per band, slots 0..127 each written exactly
// once -> no zero-init, no collisions.
__global__ __launch_bounds__(256, 3) void simexp_kernel(
    const unsigned int* __restrict__ Au, float* __restrict__ partials) {
  const int lane = threadIdx.x & 63;
  const int w = threadIdx.x >> 6;
  const int q = lane >> 4;
  const int n = lane & 15;

  // decode wave-tile index g -> (ti, tj), ti <= tj < 128
  int g = blockIdx.x * 4 + w;
  int ti = (int)((257.0f - sqrtf(66049.0f - 8.0f * (float)g)) * 0.5f);
  int start = 128 * ti - (ti * (ti - 1)) / 2;
  if (g < start) {
    ti--;
    start = 128 * ti - (ti * (ti - 1)) / 2;
  } else if (g >= start + (128 - ti)) {
    start += 128 - ti;
    ti++;
  }
  int tj = ti + (g - start);
  const bool diag = (ti == tj);

  // fragment base: page p -> 64 chunks of 16B; this lane's chunk p*64+lane
  const bf16x8* frag = (const bf16x8*)Au + lane;

  f32x4 acc[16];
#pragma unroll
  for (int i = 0; i < 16; i++)
#pragma unroll
    for (int j = 0; j < 4; j++) acc[i][j] = 0.0f;

  bf16x8 af[2][4], bf[2][4];
#pragma unroll
  for (int mi = 0; mi < 4; mi++)
    af[0][mi] = frag[(size_t)(ti * 16 + mi * 4 + 0) * 64];
#pragma unroll
  for (int ni = 0; ni < 4; ni++)
    bf[0][ni] = frag[(size_t)(tj * 16 + ni * 4 + 0) * 64];

#pragma unroll
  for (int kc = 0; kc < 4; kc++) {
    const int cur = kc & 1;
    const int nxt = cur ^ 1;
    if (kc < 3) {
#pragma unroll
      for (int mi = 0; mi < 4; mi++)
        af[nxt][mi] = frag[(size_t)(ti * 16 + mi * 4 + kc + 1) * 64];
#pragma unroll
      for (int ni = 0; ni < 4; ni++)
        bf[nxt][ni] = frag[(size_t)(tj * 16 + ni * 4 + kc + 1) * 64];
    }
#pragma unroll
    for (int mi = 0; mi < 4; mi++)
#pragma unroll
      for (int ni = 0; ni < 4; ni++)
        acc[mi * 4 + ni] = __builtin_amdgcn_mfma_f32_16x16x32_bf16(
            af[cur][mi], bf[cur][ni], acc[mi * 4 + ni], 0, 0, 0);
  }

  // epilogue: exp2, (diag-only) mask, row + column accumulation in regs
  float eaccR[16];
  float eaccC[4];
#pragma unroll
  for (int i = 0; i < 16; i++) eaccR[i] = 0.0f;
#pragma unroll
  for (int i = 0; i < 4; i++) eaccC[i] = 0.0f;
  if (diag) {
#pragma unroll
    for (int mi = 0; mi < 4; mi++)
#pragma unroll
      for (int ni = 0; ni < 4; ni++)
#pragma unroll
        for (int rg = 0; rg < 4; rg++) {
          float e = __builtin_amdgcn_exp2f(acc[mi * 4 + ni][rg]);
          // local row/col within tile; ti==tj so global offsets cancel
          e = ((mi * 16 + q * 4 + rg) == (ni * 16 + n)) ? 0.0f : e;
          eaccR[mi * 4 + rg] += e;
          eaccC[ni] += e;
        }
  } else {
#pragma unroll
    for (int mi = 0; mi < 4; mi++)
#pragma unroll
      for (int ni = 0; ni < 4; ni++)
#pragma unroll
        for (int rg = 0; rg < 4; rg++) {
          float e = __builtin_amdgcn_exp2f(acc[mi * 4 + ni][rg]);
          eaccR[mi * 4 + rg] += e;
          eaccC[ni] += e;
        }
  }

  const int dslot = tj - ti;
  // row sums: reduce across n (xor 1,2,4,8 within each q-group), store
  float* prow = partials + (size_t)dslot * NROWS + ti * 64;
#pragma unroll
  for (int mi = 0; mi < 4; mi++) {
#pragma unroll
    for (int rg = 0; rg < 4; rg++) {
      float v = eaccR[mi * 4 + rg];
      v += __shfl_xor(v, 1);
      v += __shfl_xor(v, 2);
      v += __shfl_xor(v, 4);
      v += __shfl_xor(v, 8);
      if (n == 0) prow[mi * 16 + q * 4 + rg] = v;
    }
  }
  // column sums (symmetry credit): reduce across q (xor 16,32), store
  if (!diag) {
    float* pcol = partials + (size_t)(128 - dslot) * NROWS + tj * 64;
#pragma unroll
    for (int ni = 0; ni < 4; ni++) {
      float v = eaccC[ni];
      v += __shfl_xor(v, 16);
      v += __shfl_xor(v, 32);
      if (lane < 16) pcol[ni * 16 + lane] = v;
    }
  }
}

// loss = mean over rows of log(rowsum) - pos; rowsum = sum of the row's
// 128 partial slots. 256 blocks x 256 threads: block handles 32 rows with
// an 8-way k-split (tid = ks*32 + rr), LDS reduce, one atomic per block.
__global__ __launch_bounds__(256) void finalize_kernel(
    const float* __restrict__ partials, const float* __restrict__ pos,
    float* __restrict__ out) {
  int tid = threadIdx.x;
  int rr = tid & 31;
  int ks = tid >> 5;  // 0..7
  int r = blockIdx.x * 32 + rr;
  float s = 0.0f;
#pragma unroll
  for (int k = 0; k < 16; k++)
    s += partials[(size_t)(ks * 16 + k) * NROWS + r];
  __shared__ float red[8][32];
  red[ks][rr] = s;
  __syncthreads();
  if (tid < 32) {
    float t = 0.0f;
#pragma unroll
    for (int k2 = 0; k2 < 8; k2++) t += red[k2][tid];
    float local = logf(t) - pos[blockIdx.x * 32 + tid];
#pragma unroll
    for (int off = 1; off < 32; off <<= 1) local += __shfl_xor(local, off);
    if (tid == 0) atomicAdd(out, local * (1.0f / (float)NROWS));
  }
}

extern "C" void kernel_launch(void* const* d_in, const int* in_sizes, int n_in,
                              void* d_out, int out_size, void* d_ws,
                              size_t ws_size, hipStream_t stream) {
  const float* z_i = (const float*)d_in[0];
  const float* z_j = (const float*)d_in[1];
  float* out = (float*)d_out;

  unsigned int* A = (unsigned int*)d_ws;                 // fragment-major, 2 MB
  float* partials = (float*)((char*)d_ws + (1u << 21));  // 128*8192 f32 = 4 MB
  float* pos = (float*)((char*)d_ws + (3u << 21));       // 32 KB

  prep_kernel<<<NHALF / 4, 256, 0, stream>>>(z_i, z_j, A, pos, out);
  simexp_kernel<<<NTILES / 4, 256, 0, stream>>>((const unsigned int*)A,
                                                partials);
  finalize_kernel<<<NROWS / 32, 256, 0, stream>>>(partials, pos, out);
}

// Round 7
// 81.318 us; speedup vs baseline: 1.4851x; 1.0528x over previous
//
#include <hip/hip_runtime.h>
#include <cmath>

#define DIM 128
#define NHALF 4096
#define NROWS 8192
#define NB 128       // number of 64-row bands
#define NTILES 8256  // NB*(NB+1)/2 upper-triangle 64x64 tiles
// FRAG_SCALE^2 = log2(e)/tau = 1.4426950408889634/0.5
#define FRAG_SCALE 1.69864368f

typedef __attribute__((ext_vector_type(8))) short bf16x8;
typedef __attribute__((ext_vector_type(4))) float f32x4;

static __device__ __forceinline__ unsigned short f32_to_bf16(float f) {
  unsigned int u = __float_as_uint(f);
  u = (u + 0x7FFFu + ((u >> 16) & 1u)) >> 16;
  return (unsigned short)u;
}

// VALU-pipe cross-lane add via DPP row rotate (16-lane rows on gfx9/CDNA).
// Rotating by 1,2,4,8 and adding gives an allreduce within each 16-lane
// group without touching the LDS pipe (unlike __shfl_xor -> ds_swizzle).
// dpp_ctrl must be a literal constant -> template parameter.
template <int CTRL>
static __device__ __forceinline__ float dpp_radd(float v) {
  int t = __builtin_amdgcn_update_dpp(0, __float_as_int(v), CTRL, 0xF, 0xF,
                                      false);
  return v + __int_as_float(t);
}
static __device__ __forceinline__ float row16_allreduce(float v) {
  v = dpp_radd<0x121>(v);  // row_ror:1
  v = dpp_radd<0x122>(v);  // row_ror:2
  v = dpp_radd<0x124>(v);  // row_ror:4
  v = dpp_radd<0x128>(v);  // row_ror:8
  return v;
}

// Fragment-major layout of the normalized bf16 matrix A_f:
//   group g = row>>4 (0..511), page = g*4 + kc (1 KB each).
//   Within a page: 16B chunk at offset (q*16 + n)*16 holds
//   row g*16+n, cols kc*32 + q*8 .. +8.
// Every MFMA fragment load is `base + lane*16` -> 64 lanes x 16 B fully
// contiguous (ideal coalescing; no 16-way gather).

// One wave per pair r in [0,4096): L2-normalize z_i[r], z_j[r], scale by
// sqrt(log2e/tau), write bf16 rows r and r+4096 in fragment-major order;
// pos[r]=pos[r+4096] = dot/(|zi||zj|)/tau in fp32. Also zeroes out[0].
__global__ __launch_bounds__(256) void prep_kernel(
    const float* __restrict__ z_i, const float* __restrict__ z_j,
    unsigned int* __restrict__ A, float* __restrict__ pos,
    float* __restrict__ out) {
  int wave = threadIdx.x >> 6;
  int lane = threadIdx.x & 63;
  int r = blockIdx.x * 4 + wave;
  if (blockIdx.x == 0 && threadIdx.x == 0) out[0] = 0.0f;
  float2 a = *(const float2*)(z_i + (size_t)r * DIM + 2 * lane);
  float2 b = *(const float2*)(z_j + (size_t)r * DIM + 2 * lane);
  float sa = a.x * a.x + a.y * a.y;
  float sb = b.x * b.x + b.y * b.y;
  float dp = a.x * b.x + a.y * b.y;
#pragma unroll
  for (int off = 1; off < 64; off <<= 1) {
    sa += __shfl_xor(sa, off);
    sb += __shfl_xor(sb, off);
    dp += __shfl_xor(dp, off);
  }
  float na = fmaxf(sqrtf(sa), 1e-8f);
  float nb = fmaxf(sqrtf(sb), 1e-8f);
  float si = FRAG_SCALE / na;
  float sj = FRAG_SCALE / nb;
  unsigned int pa = (unsigned int)f32_to_bf16(a.x * si) |
                    ((unsigned int)f32_to_bf16(a.y * si) << 16);
  unsigned int pb = (unsigned int)f32_to_bf16(b.x * sj) |
                    ((unsigned int)f32_to_bf16(b.y * sj) << 16);
  // fragment-major scatter store (lane holds cols 2*lane, 2*lane+1):
  // kc = lane>>4, q = (lane>>2)&3, byte-quad bq = lane&3, n = r&15.
  int rg = r >> 4;
  int n = r & 15;
  int kc = lane >> 4;
  int q = (lane >> 2) & 3;
  int bq = lane & 3;
  int off4 = rg * 1024 + kc * 256 + q * 64 + n * 4 + bq;
  A[off4] = pa;
  A[off4 + 262144] = pb;  // z_j groups start at group 256
  if (lane == 0) {
    float p = dp / (na * nb) * 2.0f;  // /tau, tau=0.5
    pos[r] = p;
    pos[r + NHALF] = p;
  }
}

// One wave = one independent 64x64 upper-triangle tile (ti<=tj over 128
// bands of 64 rows). No LDS, no barriers, no atomics. Fragment loads are
// fully coalesced (fragment-major A). Single-buffered kc loop +
// launch_bounds(256,4) keeps the footprint at ~64 VGPR + 64 AGPR -> 4
// waves/SIMD of TLP. Row exp-sums reduce on the VALU pipe via DPP row_ror
// (LDS pipe untouched) and store to disjoint slot (tj-ti) of
// partials[128][8192]; col-side symmetry credit (2 shuffles) stores to
// slot 128-(tj-ti). Per band, slots 0..127 each written exactly once ->
// no zero-init, no collisions.
__global__ __launch_bounds__(256, 4) void simexp_kernel(
    const unsigned int* __restrict__ Au, float* __restrict__ partials) {
  const int lane = threadIdx.x & 63;
  const int w = threadIdx.x >> 6;
  const int q = lane >> 4;
  const int n = lane & 15;

  // decode wave-tile index g -> (ti, tj), ti <= tj < 128
  int g = blockIdx.x * 4 + w;
  int ti = (int)((257.0f - sqrtf(66049.0f - 8.0f * (float)g)) * 0.5f);
  int start = 128 * ti - (ti * (ti - 1)) / 2;
  if (g < start) {
    ti--;
    start = 128 * ti - (ti * (ti - 1)) / 2;
  } else if (g >= start + (128 - ti)) {
    start += 128 - ti;
    ti++;
  }
  int tj = ti + (g - start);
  const bool diag = (ti == tj);

  // fragment base: page p -> 64 chunks of 16B; this lane's chunk p*64+lane
  const bf16x8* frag = (const bf16x8*)Au + lane;

  f32x4 acc[16];
#pragma unroll
  for (int i = 0; i < 16; i++)
#pragma unroll
    for (int j = 0; j < 4; j++) acc[i][j] = 0.0f;

#pragma unroll
  for (int kc = 0; kc < 4; kc++) {
    bf16x8 af[4], bfr[4];
#pragma unroll
    for (int mi = 0; mi < 4; mi++)
      af[mi] = frag[(size_t)(ti * 16 + mi * 4 + kc) * 64];
#pragma unroll
    for (int ni = 0; ni < 4; ni++)
      bfr[ni] = frag[(size_t)(tj * 16 + ni * 4 + kc) * 64];
#pragma unroll
    for (int mi = 0; mi < 4; mi++)
#pragma unroll
      for (int ni = 0; ni < 4; ni++)
        acc[mi * 4 + ni] = __builtin_amdgcn_mfma_f32_16x16x32_bf16(
            af[mi], bfr[ni], acc[mi * 4 + ni], 0, 0, 0);
  }

  // epilogue: exp2, (diag-only) mask, row + column accumulation in regs
  float eaccR[16];
  float eaccC[4];
#pragma unroll
  for (int i = 0; i < 16; i++) eaccR[i] = 0.0f;
#pragma unroll
  for (int i = 0; i < 4; i++) eaccC[i] = 0.0f;
  if (diag) {
#pragma unroll
    for (int mi = 0; mi < 4; mi++)
#pragma unroll
      for (int ni = 0; ni < 4; ni++)
#pragma unroll
        for (int rg = 0; rg < 4; rg++) {
          float e = __builtin_amdgcn_exp2f(acc[mi * 4 + ni][rg]);
          // local row/col within tile; ti==tj so global offsets cancel
          e = ((mi * 16 + q * 4 + rg) == (ni * 16 + n)) ? 0.0f : e;
          eaccR[mi * 4 + rg] += e;
          eaccC[ni] += e;
        }
  } else {
#pragma unroll
    for (int mi = 0; mi < 4; mi++)
#pragma unroll
      for (int ni = 0; ni < 4; ni++)
#pragma unroll
        for (int rg = 0; rg < 4; rg++) {
          float e = __builtin_amdgcn_exp2f(acc[mi * 4 + ni][rg]);
          eaccR[mi * 4 + rg] += e;
          eaccC[ni] += e;
        }
  }

  const int dslot = tj - ti;
  // row sums: DPP allreduce within each 16-lane group (VALU pipe), store
  float* prow = partials + (size_t)dslot * NROWS + ti * 64;
#pragma unroll
  for (int mi = 0; mi < 4; mi++) {
#pragma unroll
    for (int rg = 0; rg < 4; rg++) {
      float v = row16_allreduce(eaccR[mi * 4 + rg]);
      if (n == 0) prow[mi * 16 + q * 4 + rg] = v;
    }
  }
  // column sums (symmetry credit): reduce across q (xor 16,32), store
  if (!diag) {
    float* pcol = partials + (size_t)(128 - dslot) * NROWS + tj * 64;
#pragma unroll
    for (int ni = 0; ni < 4; ni++) {
      float v = eaccC[ni];
      v += __shfl_xor(v, 16);
      v += __shfl_xor(v, 32);
      if (lane < 16) pcol[ni * 16 + lane] = v;
    }
  }
}

// loss = mean over rows of log(rowsum) - pos; rowsum = sum of the row's
// 128 partial slots. 256 blocks x 256 threads: block handles 32 rows with
// an 8-way k-split (tid = ks*32 + rr), LDS reduce, one atomic per block.
__global__ __launch_bounds__(256) void finalize_kernel(
    const float* __restrict__ partials, const float* __restrict__ pos,
    float* __restrict__ out) {
  int tid = threadIdx.x;
  int rr = tid & 31;
  int ks = tid >> 5;  // 0..7
  int r = blockIdx.x * 32 + rr;
  float s = 0.0f;
#pragma unroll
  for (int k = 0; k < 16; k++)
    s += partials[(size_t)(ks * 16 + k) * NROWS + r];
  __shared__ float red[8][32];
  red[ks][rr] = s;
  __syncthreads();
  if (tid < 32) {
    float t = 0.0f;
#pragma unroll
    for (int k2 = 0; k2 < 8; k2++) t += red[k2][tid];
    float local = logf(t) - pos[blockIdx.x * 32 + tid];
#pragma unroll
    for (int off = 1; off < 32; off <<= 1) local += __shfl_xor(local, off);
    if (tid == 0) atomicAdd(out, local * (1.0f / (float)NROWS));
  }
}

extern "C" void kernel_launch(void* const* d_in, const int* in_sizes, int n_in,
                              void* d_out, int out_size, void* d_ws,
                              size_t ws_size, hipStream_t stream) {
  const float* z_i = (const float*)d_in[0];
  const float* z_j = (const float*)d_in[1];
  float* out = (float*)d_out;

  unsigned int* A = (unsigned int*)d_ws;                 // fragment-major, 2 MB
  float* partials = (float*)((char*)d_ws + (1u << 21));  // 128*8192 f32 = 4 MB
  float* pos = (float*)((char*)d_ws + (3u << 21));       // 32 KB

  prep_kernel<<<NHALF / 4, 256, 0, stream>>>(z_i, z_j, A, pos, out);
  simexp_kernel<<<NTILES / 4, 256, 0, stream>>>((const unsigned int*)A,
                                                partials);
  finalize_kernel<<<NROWS / 32, 256, 0, stream>>>(partials, pos, out);
}